// Round 16
// baseline (282.712 us; speedup 1.0000x reference)
//
#include <hip/hip_runtime.h>
#include <hip/hip_bf16.h>

#define NB 8
#define NT 8192
#define NO 1024
#define DD 384
#define K1 1152
#define M1 65536
#define MO 8192

typedef __attribute__((ext_vector_type(8))) short bf16x8;
typedef __attribute__((ext_vector_type(4))) float f32x4;
typedef __attribute__((ext_vector_type(4))) unsigned short u16x4;

__device__ __forceinline__ unsigned short f2bf(float f) {
    union { float f; unsigned u; } v; v.f = f;
    unsigned r = v.u + 0x7FFFu + ((v.u >> 16) & 1u);
    return (unsigned short)(r >> 16);
}
__device__ __forceinline__ float bf2f(unsigned short h) {
    union { unsigned u; float f; } v; v.u = ((unsigned)h) << 16;
    return v.f;
}
__device__ __forceinline__ bf16x8 pack8(f32x4 a, f32x4 b) {
    bf16x8 r;
    r[0] = (short)f2bf(a[0]); r[1] = (short)f2bf(a[1]);
    r[2] = (short)f2bf(a[2]); r[3] = (short)f2bf(a[3]);
    r[4] = (short)f2bf(b[0]); r[5] = (short)f2bf(b[1]);
    r[6] = (short)f2bf(b[2]); r[7] = (short)f2bf(b[3]);
    return r;
}
__device__ __forceinline__ void gload16(const void* g, void* l) {
    __builtin_amdgcn_global_load_lds(
        (const __attribute__((address_space(1))) unsigned int*)g,
        (__attribute__((address_space(3))) unsigned int*)l, 16, 0, 0);
}

// ---------- prep ----------
__global__ void k_cvt4(const float* __restrict__ s, unsigned short* __restrict__ d, int n) {
    int i = (blockIdx.x * blockDim.x + threadIdx.x) * 4;
    if (i >= n) return;
    f32x4 v = *(const f32x4*)(s + i);
    u16x4 o;
    o[0] = f2bf(v[0]); o[1] = f2bf(v[1]); o[2] = f2bf(v[2]); o[3] = f2bf(v[3]);
    *(u16x4*)(d + i) = o;
}
__global__ void k_tr(const float* __restrict__ s, unsigned short* __restrict__ d, int K, int N) {
    int k = blockIdx.x;
    int n = blockIdx.y * blockDim.x + threadIdx.x;
    if (n < N) d[n * K + k] = f2bf(s[k * N + n]);
}

// ---------- two-stage sum-of-squares ----------
__global__ void k_ss1(const float* __restrict__ p, float* __restrict__ partial, int n4) {
    __shared__ float wsum[4];
    int stride = gridDim.x * blockDim.x;
    float s = 0.f;
    for (int i = blockIdx.x * blockDim.x + threadIdx.x; i < n4; i += stride) {
        f32x4 v = *(const f32x4*)(p + i * 4);
        s += v[0] * v[0] + v[1] * v[1] + v[2] * v[2] + v[3] * v[3];
    }
#pragma unroll
    for (int off = 32; off; off >>= 1) s += __shfl_down(s, off, 64);
    if ((threadIdx.x & 63) == 0) wsum[threadIdx.x >> 6] = s;
    __syncthreads();
    if (threadIdx.x == 0)
        partial[blockIdx.x] = wsum[0] + wsum[1] + wsum[2] + wsum[3];
}
__global__ void k_ss2(const float* __restrict__ partial, float* __restrict__ o) {
    float s = partial[threadIdx.x];
#pragma unroll
    for (int off = 32; off; off >>= 1) s += __shfl_down(s, off, 64);
    __shared__ float w0, w1;
    if (threadIdx.x == 0) w0 = s;
    if (threadIdx.x == 64) w1 = s;
    __syncthreads();
    if (threadIdx.x == 0) o[0] = w0 + w1;
}
__global__ void k_normcvt(const float* __restrict__ p, const float* __restrict__ ss,
                          unsigned short* __restrict__ o) {
    int i = (blockIdx.x * blockDim.x + threadIdx.x) * 8;
    float s = rsqrtf(ss[0]);
    f32x4 a = *(const f32x4*)(p + i), b = *(const f32x4*)(p + i + 4);
    a *= s; b *= s;
    *(bf16x8*)(o + i) = pack8(a, b);
}

// ---------- CSR build ----------
__global__ void k_hist(const int* __restrict__ edges, int* __restrict__ cnt) {
    int i = blockIdx.x * 256 + threadIdx.x;
    int2 e = *(const int2*)&edges[(size_t)i * 2];
    int b = i >> 13;
    atomicAdd(&cnt[(b << 10) + e.x], 1);
    atomicAdd(&cnt[(b << 10) + e.y], 1);
}
__global__ void k_scan(const int* __restrict__ cnt, int* __restrict__ offs) {
    __shared__ int a[1024];
    int b = blockIdx.x, t = threadIdx.x;
    int own = cnt[(b << 10) + t];
    a[t] = own;
    __syncthreads();
    for (int s = 1; s < 1024; s <<= 1) {
        int v = (t >= s) ? a[t - s] : 0;
        __syncthreads();
        a[t] += v;
        __syncthreads();
    }
    offs[(b << 10) + t] = a[t] - own;
}
__global__ void k_fill(const int* __restrict__ edges, const int* __restrict__ offs,
                       int* __restrict__ cur, int* __restrict__ elist) {
    int i = blockIdx.x * 256 + threadIdx.x;
    int2 e = *(const int2*)&edges[(size_t)i * 2];
    int b = i >> 13, t = i & (NT - 1);
    int ps = atomicAdd(&cur[(b << 10) + e.x], 1);
    elist[(b << 14) + offs[(b << 10) + e.x] + ps] = t * 2;
    int po = atomicAdd(&cur[(b << 10) + e.y], 1);
    elist[(b << 14) + offs[(b << 10) + e.y] + po] = t * 2 + 1;
}
__global__ void k_pool(const unsigned short* __restrict__ sob, const int* __restrict__ cnt,
                       const int* __restrict__ offs, const int* __restrict__ elist,
                       float* __restrict__ pooled) {
    int w = (blockIdx.x * 256 + threadIdx.x) >> 6;
    int lane = threadIdx.x & 63;
    if (lane >= 48) return;
    int b = w >> 10, o = w & (NO - 1);
    int len = cnt[(b << 10) + o];
    const int* lst = elist + (b << 14) + offs[(b << 10) + o];
    f32x4 a0 = {0.f, 0.f, 0.f, 0.f}, a1 = {0.f, 0.f, 0.f, 0.f};
    f32x4 c0 = {0.f, 0.f, 0.f, 0.f}, c1 = {0.f, 0.f, 0.f, 0.f};
    int j = 0;
    for (; j + 1 < len; j += 2) {
        int e0 = lst[j], e1 = lst[j + 1];
        bf16x8 v0 = *(const bf16x8*)(sob + ((size_t)((b << 13) + (e0 >> 1))) * 768 + (e0 & 1) * DD + lane * 8);
        bf16x8 v1 = *(const bf16x8*)(sob + ((size_t)((b << 13) + (e1 >> 1))) * 768 + (e1 & 1) * DD + lane * 8);
        a0[0] += bf2f((unsigned short)v0[0]); a0[1] += bf2f((unsigned short)v0[1]);
        a0[2] += bf2f((unsigned short)v0[2]); a0[3] += bf2f((unsigned short)v0[3]);
        a1[0] += bf2f((unsigned short)v0[4]); a1[1] += bf2f((unsigned short)v0[5]);
        a1[2] += bf2f((unsigned short)v0[6]); a1[3] += bf2f((unsigned short)v0[7]);
        c0[0] += bf2f((unsigned short)v1[0]); c0[1] += bf2f((unsigned short)v1[1]);
        c0[2] += bf2f((unsigned short)v1[2]); c0[3] += bf2f((unsigned short)v1[3]);
        c1[0] += bf2f((unsigned short)v1[4]); c1[1] += bf2f((unsigned short)v1[5]);
        c1[2] += bf2f((unsigned short)v1[6]); c1[3] += bf2f((unsigned short)v1[7]);
    }
    if (j < len) {
        int e0 = lst[j];
        bf16x8 v0 = *(const bf16x8*)(sob + ((size_t)((b << 13) + (e0 >> 1))) * 768 + (e0 & 1) * DD + lane * 8);
        a0[0] += bf2f((unsigned short)v0[0]); a0[1] += bf2f((unsigned short)v0[1]);
        a0[2] += bf2f((unsigned short)v0[2]); a0[3] += bf2f((unsigned short)v0[3]);
        a1[0] += bf2f((unsigned short)v0[4]); a1[1] += bf2f((unsigned short)v0[5]);
        a1[2] += bf2f((unsigned short)v0[6]); a1[3] += bf2f((unsigned short)v0[7]);
    }
    a0 += c0; a1 += c1;
    float* dst = pooled + ((size_t)((b << 10) + o)) * DD + lane * 8;
    *(f32x4*)dst = a0;
    *(f32x4*)(dst + 4) = a1;
}

// ---------- 256x384-tile pipelined gather-GEMM1 (160KB LDS, 16 waves, 1 block/CU) ----------
// hbuf = relu(gather(triple) @ w1aT^T + b1a); K=1152, 18 K-steps of 64. Full N-panel:
// A staged once (no n-re-read), B re-staged per 256-row m-block (256 blocks total).
// 1024 threads = 16 waves (4m x 4n), wave tile 64x96, acc 4x6 (same as r14).
// Grid 256; chunk swizzle (32 ids = 1 batch) keeps batch->XCD.
__launch_bounds__(1024, 1)
__global__ void gemm_g1(const unsigned short* __restrict__ objb,
                        const float* __restrict__ predf,
                        const int* __restrict__ edges,
                        const unsigned short* __restrict__ Bt,
                        const float* __restrict__ bias,
                        unsigned short* __restrict__ outb)
{
    const int tid = threadIdx.x;
    const int lane = tid & 63;
    const int d = blockIdx.x;
    const int bid = (d & 7) * 32 + (d >> 3);       // bijective; 32 ids = 1 batch per XCD
    const int m0 = bid * 256;

    __shared__ unsigned short lds[2][40960];       // [buf][A:0..16383 | B:16384..40959] = 160KB

    const int rb = tid >> 3;                       // 0..127
    const int c8 = ((tid & 7) ^ (rb & 7)) * 8;     // inverse-swizzled source k-offset

    const int bb = (m0 >> 13) << 10;
    int er0[2], er1[2];
#pragma unroll
    for (int i = 0; i < 2; ++i) {
        int2 e = *(const int2*)&edges[(size_t)(m0 + i * 128 + rb) * 2];
        er0[i] = bb + e.x;
        er1[i] = bb + e.y;
    }

    f32x4 acc[4][6];
#pragma unroll
    for (int i = 0; i < 4; ++i)
#pragma unroll
        for (int j = 0; j < 6; ++j) acc[i][j] = (f32x4){0.f, 0.f, 0.f, 0.f};

    const int wid = tid >> 6, wm = wid >> 2, wn = wid & 3;
    const int l16 = lane & 15, lg = lane >> 4;

    // prologue: tile 0 (seg 0 = subj) — A 2 chunks, B 3 chunks per thread
#pragma unroll
    for (int i = 0; i < 2; ++i)
        gload16(objb + (size_t)er0[i] * DD + c8, &lds[0][i * 8192 + tid * 8]);
#pragma unroll
    for (int i = 0; i < 3; ++i)
        gload16(Bt + (size_t)(i * 128 + rb) * K1 + c8, &lds[0][16384 + i * 8192 + tid * 8]);

    const int nsteps = K1 / 64;    // 18
    for (int t = 0; t < nsteps; ++t) {
        const int cur = t & 1;
        const int tn = t + 1;
        if (tn < nsteps) {
            const int nseg = tn / 6;
            const int ko = (tn - nseg * 6) * 64;   // local offset within segment
            if (nseg == 1) {
                // pred: f32 reg loads (implicit precise wait before pack8 retires
                // them AND all older staging loads); B gloads stay in flight.
                f32x4 pf[2][2];
#pragma unroll
                for (int i = 0; i < 2; ++i) {
                    const float* p = predf + (size_t)(m0 + i * 128 + rb) * DD + ko + c8;
                    pf[i][0] = *(const f32x4*)p;
                    pf[i][1] = *(const f32x4*)(p + 4);
                }
#pragma unroll
                for (int i = 0; i < 3; ++i)
                    gload16(Bt + (size_t)(i * 128 + rb) * K1 + tn * 64 + c8,
                            &lds[cur ^ 1][16384 + i * 8192 + tid * 8]);
#pragma unroll
                for (int i = 0; i < 2; ++i)
                    *(bf16x8*)(&lds[cur ^ 1][i * 8192 + tid * 8]) = pack8(pf[i][0], pf[i][1]);
            } else {
#pragma unroll
                for (int i = 0; i < 2; ++i) {
                    int row = (nseg == 0) ? er0[i] : er1[i];
                    gload16(objb + (size_t)row * DD + ko + c8, &lds[cur ^ 1][i * 8192 + tid * 8]);
                }
#pragma unroll
                for (int i = 0; i < 3; ++i)
                    gload16(Bt + (size_t)(i * 128 + rb) * K1 + tn * 64 + c8,
                            &lds[cur ^ 1][16384 + i * 8192 + tid * 8]);
                asm volatile("s_waitcnt vmcnt(5)" ::: "memory");
            }
        } else {
            asm volatile("s_waitcnt vmcnt(0)" ::: "memory");
        }
        __builtin_amdgcn_s_barrier();
        const unsigned short* At = &lds[cur][0];
        const unsigned short* Bl = &lds[cur][16384];
#pragma unroll
        for (int kt = 0; kt < 2; ++kt) {
            const int cs = ((kt * 4 + lg) ^ (l16 & 7)) * 8;
            bf16x8 af[4], bfr[6];
#pragma unroll
            for (int mt = 0; mt < 4; ++mt)
                af[mt] = *(const bf16x8*)(At + (wm * 64 + mt * 16 + l16) * 64 + cs);
#pragma unroll
            for (int nn = 0; nn < 6; ++nn)
                bfr[nn] = *(const bf16x8*)(Bl + (wn * 96 + nn * 16 + l16) * 64 + cs);
#pragma unroll
            for (int mt = 0; mt < 4; ++mt)
#pragma unroll
                for (int nn = 0; nn < 6; ++nn)
                    acc[mt][nn] = __builtin_amdgcn_mfma_f32_16x16x32_bf16(af[mt], bfr[nn], acc[mt][nn], 0, 0, 0);
        }
        asm volatile("s_waitcnt lgkmcnt(0)" ::: "memory");
        __builtin_amdgcn_s_barrier();
    }

#pragma unroll
    for (int nn = 0; nn < 6; ++nn) {
        int gn = wn * 96 + nn * 16 + l16;
        float bv = bias[gn];
#pragma unroll
        for (int mt = 0; mt < 4; ++mt) {
            int rbase = wm * 64 + mt * 16 + lg * 4;
#pragma unroll
            for (int rg = 0; rg < 4; ++rg) {
                int gr = m0 + rbase + rg;
                float v = fmaxf(acc[mt][nn][rg] + bv, 0.0f);
                outb[(size_t)gr * DD + gn] = f2bf(v);
            }
        }
    }
}

// ---------- 128x192-tile pipelined GEMM (80KB LDS, 2 blocks/CU) — K=384 GEMMs ----------
template <int EPI>
__launch_bounds__(256, 2)
__global__ void gemm_p(const unsigned short* __restrict__ Abf,
                       const unsigned short* __restrict__ Bt,
                       const float* __restrict__ bias,
                       unsigned short* __restrict__ outb,
                       float* __restrict__ outf,
                       int K, int ldC, int nbn, int osplit, int oadd)
{
    const int tid = threadIdx.x;
    const int lane = tid & 63;
    const int d = blockIdx.x;
    const int chunk = gridDim.x >> 3;
    const int bid = (d & 7) * chunk + (d >> 3);
    const int xb = bid / nbn, nb = bid - xb * nbn;
    const int m0 = xb * 128;
    const int btrow = nb * 192 + (nb >= osplit ? oadd : 0);
    const int col0 = nb * 192;

    __shared__ unsigned short lds[2][20480];

    const int rb = tid >> 3;
    const int c8 = ((tid & 7) ^ (rb & 7)) * 8;

    f32x4 acc[4][6];
#pragma unroll
    for (int i = 0; i < 4; ++i)
#pragma unroll
        for (int j = 0; j < 6; ++j) acc[i][j] = (f32x4){0.f, 0.f, 0.f, 0.f};

    const int wid = tid >> 6, wm = wid >> 1, wn = wid & 1;
    const int l16 = lane & 15, lg = lane >> 4;

#define STAGE_P(BUF, KK)                                                                   \
    {                                                                                      \
        _Pragma("unroll")                                                                  \
        for (int i = 0; i < 6; ++i)                                                        \
            gload16(Bt + (size_t)(btrow + i * 32 + rb) * K + (KK) + c8,                    \
                    &lds[BUF][8192 + i * 2048 + tid * 8]);                                 \
        _Pragma("unroll")                                                                  \
        for (int i = 0; i < 4; ++i)                                                        \
            gload16(Abf + (size_t)(m0 + i * 32 + rb) * K + (KK) + c8,                      \
                    &lds[BUF][i * 2048 + tid * 8]);                                        \
    }

    const int nt = K / 64;
    STAGE_P(0, 0)
    for (int t = 0; t < nt; ++t) {
        const int cur = t & 1;
        if (t + 1 < nt) {
            STAGE_P(cur ^ 1, (t + 1) * 64)
            asm volatile("s_waitcnt vmcnt(10)" ::: "memory");
        } else {
            asm volatile("s_waitcnt vmcnt(0)" ::: "memory");
        }
        __builtin_amdgcn_s_barrier();
        const unsigned short* At = &lds[cur][0];
        const unsigned short* Bl = &lds[cur][8192];
#pragma unroll
        for (int kt = 0; kt < 2; ++kt) {
            const int cs = ((kt * 4 + lg) ^ (l16 & 7)) * 8;
            bf16x8 af[4], bfr[6];
#pragma unroll
            for (int mt = 0; mt < 4; ++mt)
                af[mt] = *(const bf16x8*)(At + (wm * 64 + mt * 16 + l16) * 64 + cs);
#pragma unroll
            for (int nn = 0; nn < 6; ++nn)
                bfr[nn] = *(const bf16x8*)(Bl + (wn * 96 + nn * 16 + l16) * 64 + cs);
#pragma unroll
            for (int mt = 0; mt < 4; ++mt)
#pragma unroll
                for (int nn = 0; nn < 6; ++nn)
                    acc[mt][nn] = __builtin_amdgcn_mfma_f32_16x16x32_bf16(af[mt], bfr[nn], acc[mt][nn], 0, 0, 0);
        }
        asm volatile("s_waitcnt lgkmcnt(0)" ::: "memory");
        __builtin_amdgcn_s_barrier();
    }
#undef STAGE_P

#pragma unroll
    for (int nn = 0; nn < 6; ++nn) {
        int gnl = wn * 96 + nn * 16 + l16;
        float bv = bias[btrow + gnl];
#pragma unroll
        for (int mt = 0; mt < 4; ++mt) {
            int rbase = wm * 64 + mt * 16 + lg * 4;
#pragma unroll
            for (int rg = 0; rg < 4; ++rg) {
                int gr = m0 + rbase + rg;
                float v = fmaxf(acc[mt][nn][rg] + bv, 0.0f);
                if (EPI == 0) outb[(size_t)gr * ldC + col0 + gnl] = f2bf(v);
                else          outf[(size_t)gr * ldC + col0 + gnl] = v;
            }
        }
    }
}

extern "C" void kernel_launch(void* const* d_in, const int* in_sizes, int n_in,
                              void* d_out, int out_size, void* d_ws, size_t ws_size,
                              hipStream_t stream)
{
    const float* obj  = (const float*)d_in[0];
    const float* pred = (const float*)d_in[1];
    const int* edges  = (const int*)d_in[2];
    const float* w1a  = (const float*)d_in[3];
    const float* b1a  = (const float*)d_in[4];
    const float* w1b  = (const float*)d_in[5];
    const float* b1b  = (const float*)d_in[6];
    const float* w2a  = (const float*)d_in[7];
    const float* b2a  = (const float*)d_in[8];
    const float* w2b  = (const float*)d_in[9];
    const float* b2b  = (const float*)d_in[10];

    float* out_obj = (float*)d_out;                  // [8192][384] f32
    float* newp    = out_obj + (size_t)MO * DD;      // [65536][384] f32
    unsigned short* sob = (unsigned short*)newp;     // temp alias: [65536][768] bf16

    unsigned short* objb = (unsigned short*)d_ws;
    unsigned short* w1aT = objb + (size_t)NB * NO * DD;
    unsigned short* w1bT = w1aT + (size_t)DD * K1;
    unsigned short* w2aT = w1bT + (size_t)K1 * DD;
    unsigned short* w2bT = w2aT + (size_t)DD * DD;
    unsigned short* hbuf = w2bT + (size_t)DD * DD;                 // [65536][384] bf16
    float* pooled = (float*)(hbuf + (size_t)M1 * DD);              // [8192][384] f32
    float* sumsq  = pooled + (size_t)MO * DD;                      // 1 f32 (+pad)
    unsigned short* hid2 = (unsigned short*)(sumsq + 4);           // [8192][384] bf16
    int* cnt   = (int*)(hid2 + (size_t)MO * DD);                   // 8192
    int* cur   = cnt + NB * NO;
    int* offs  = cur + NB * NO;
    int* elist = offs + NB * NO;                                   // 131072
    float* partial = (float*)(elist + 2 * M1);                     // 128
    unsigned short* poolb = objb;                                  // alias: objb dead after GEMM1

    // prep
    hipLaunchKernelGGL(k_cvt4, dim3(3072), dim3(256), 0, stream, obj, objb, NB * NO * DD);
    hipLaunchKernelGGL(k_tr, dim3(K1, 3), dim3(128), 0, stream, w1a, w1aT, K1, DD);
    hipLaunchKernelGGL(k_tr, dim3(DD, 9), dim3(128), 0, stream, w1b, w1bT, DD, K1);
    hipLaunchKernelGGL(k_tr, dim3(DD, 3), dim3(128), 0, stream, w2a, w2aT, DD, DD);
    hipLaunchKernelGGL(k_tr, dim3(DD, 3), dim3(128), 0, stream, w2b, w2bT, DD, DD);
    hipMemsetAsync(cnt, 0, 2 * NB * NO * sizeof(int), stream);

    // GEMM1: hbuf = relu(gather(triple) @ w1a + b1a) — 256 blocks x 1024 thr, full N panel
    hipLaunchKernelGGL(gemm_g1, dim3(M1 / 256), dim3(1024), 0, stream,
                       objb, pred, edges, w1aT, b1a, hbuf);

    // GEMM2 s+o -> sob: 512m x 4n = 2048 blocks; nb<2 -> w1b rows nb*192 (s),
    // nb>=2 -> rows nb*192+384 (o); out cols nb*192 of ld=768.
    hipLaunchKernelGGL((gemm_p<0>), dim3(4 * M1 / 128), dim3(256), 0, stream,
                       hbuf, w1bT, b1b, sob, (float*)nullptr, DD, 2 * DD, 4, 2, DD);

    // CSR build + pooled gather-reduce
    hipLaunchKernelGGL(k_hist, dim3(256), dim3(256), 0, stream, edges, cnt);
    hipLaunchKernelGGL(k_scan, dim3(8), dim3(1024), 0, stream, cnt, offs);
    hipLaunchKernelGGL(k_fill, dim3(256), dim3(256), 0, stream, edges, offs, cur, elist);
    hipLaunchKernelGGL(k_pool, dim3(2048), dim3(256), 0, stream, sob, cnt, offs, elist, pooled);

    // newp = relu(h @ w1b[:,384:768] + b1b[384:768]) — rows 384+nb*192 (osplit=0, oadd=384)
    hipLaunchKernelGGL((gemm_p<2>), dim3(2 * M1 / 128), dim3(256), 0, stream,
                       hbuf, w1bT, b1b, (unsigned short*)nullptr, newp, DD, DD, 2, 0, DD);

    // ||pooled||^2 two-stage, then normalize+cvt
    hipLaunchKernelGGL(k_ss1, dim3(128), dim3(256), 0, stream, pooled, partial, MO * DD / 4);
    hipLaunchKernelGGL(k_ss2, dim3(1), dim3(128), 0, stream, partial, sumsq);
    hipLaunchKernelGGL(k_normcvt, dim3(1536), dim3(256), 0, stream, pooled, sumsq, poolb);

    // D1: hid2 = relu(poolb @ w2a + b2a) — 64m x 2n = 128 blocks
    hipLaunchKernelGGL((gemm_p<0>), dim3(2 * MO / 128), dim3(256), 0, stream,
                       poolb, w2aT, b2a, hid2, (float*)nullptr, DD, DD, 2, 2, 0);

    // D2: out_obj = relu(hid2 @ w2b + b2b)
    hipLaunchKernelGGL((gemm_p<2>), dim3(2 * MO / 128), dim3(256), 0, stream,
                       hid2, w2bT, b2b, (unsigned short*)nullptr, out_obj, DD, DD, 2, 2, 0);
}

// Round 17
// 245.175 us; speedup vs baseline: 1.1531x; 1.1531x over previous
//
#include <hip/hip_runtime.h>
#include <hip/hip_bf16.h>

#define NB 8
#define NT 8192
#define NO 1024
#define DD 384
#define K1 1152
#define M1 65536
#define MO 8192

typedef __attribute__((ext_vector_type(8))) short bf16x8;
typedef __attribute__((ext_vector_type(4))) float f32x4;
typedef __attribute__((ext_vector_type(4))) unsigned short u16x4;

__device__ __forceinline__ unsigned short f2bf(float f) {
    union { float f; unsigned u; } v; v.f = f;
    unsigned r = v.u + 0x7FFFu + ((v.u >> 16) & 1u);
    return (unsigned short)(r >> 16);
}
__device__ __forceinline__ float bf2f(unsigned short h) {
    union { unsigned u; float f; } v; v.u = ((unsigned)h) << 16;
    return v.f;
}
__device__ __forceinline__ bf16x8 pack8(f32x4 a, f32x4 b) {
    bf16x8 r;
    r[0] = (short)f2bf(a[0]); r[1] = (short)f2bf(a[1]);
    r[2] = (short)f2bf(a[2]); r[3] = (short)f2bf(a[3]);
    r[4] = (short)f2bf(b[0]); r[5] = (short)f2bf(b[1]);
    r[6] = (short)f2bf(b[2]); r[7] = (short)f2bf(b[3]);
    return r;
}
__device__ __forceinline__ void gload16(const void* g, void* l) {
    __builtin_amdgcn_global_load_lds(
        (const __attribute__((address_space(1))) unsigned int*)g,
        (__attribute__((address_space(3))) unsigned int*)l, 16, 0, 0);
}

// ---------- prep ----------
__global__ void k_cvt4(const float* __restrict__ s, unsigned short* __restrict__ d, int n) {
    int i = (blockIdx.x * blockDim.x + threadIdx.x) * 4;
    if (i >= n) return;
    f32x4 v = *(const f32x4*)(s + i);
    u16x4 o;
    o[0] = f2bf(v[0]); o[1] = f2bf(v[1]); o[2] = f2bf(v[2]); o[3] = f2bf(v[3]);
    *(u16x4*)(d + i) = o;
}
__global__ void k_tr(const float* __restrict__ s, unsigned short* __restrict__ d, int K, int N) {
    int k = blockIdx.x;
    int n = blockIdx.y * blockDim.x + threadIdx.x;
    if (n < N) d[n * K + k] = f2bf(s[k * N + n]);
}

// ---------- two-stage sum-of-squares ----------
__global__ void k_ss1(const float* __restrict__ p, float* __restrict__ partial, int n4) {
    __shared__ float wsum[4];
    int stride = gridDim.x * blockDim.x;
    float s = 0.f;
    for (int i = blockIdx.x * blockDim.x + threadIdx.x; i < n4; i += stride) {
        f32x4 v = *(const f32x4*)(p + i * 4);
        s += v[0] * v[0] + v[1] * v[1] + v[2] * v[2] + v[3] * v[3];
    }
#pragma unroll
    for (int off = 32; off; off >>= 1) s += __shfl_down(s, off, 64);
    if ((threadIdx.x & 63) == 0) wsum[threadIdx.x >> 6] = s;
    __syncthreads();
    if (threadIdx.x == 0)
        partial[blockIdx.x] = wsum[0] + wsum[1] + wsum[2] + wsum[3];
}
__global__ void k_ss2(const float* __restrict__ partial, float* __restrict__ o) {
    float s = partial[threadIdx.x];
#pragma unroll
    for (int off = 32; off; off >>= 1) s += __shfl_down(s, off, 64);
    __shared__ float w0, w1;
    if (threadIdx.x == 0) w0 = s;
    if (threadIdx.x == 64) w1 = s;
    __syncthreads();
    if (threadIdx.x == 0) o[0] = w0 + w1;
}
__global__ void k_normcvt(const float* __restrict__ p, const float* __restrict__ ss,
                          unsigned short* __restrict__ o) {
    int i = (blockIdx.x * blockDim.x + threadIdx.x) * 8;
    float s = rsqrtf(ss[0]);
    f32x4 a = *(const f32x4*)(p + i), b = *(const f32x4*)(p + i + 4);
    a *= s; b *= s;
    *(bf16x8*)(o + i) = pack8(a, b);
}

// ---------- CSR build ----------
__global__ void k_hist(const int* __restrict__ edges, int* __restrict__ cnt) {
    int i = blockIdx.x * 256 + threadIdx.x;
    int2 e = *(const int2*)&edges[(size_t)i * 2];
    int b = i >> 13;
    atomicAdd(&cnt[(b << 10) + e.x], 1);
    atomicAdd(&cnt[(b << 10) + e.y], 1);
}
__global__ void k_scan(const int* __restrict__ cnt, int* __restrict__ offs) {
    __shared__ int a[1024];
    int b = blockIdx.x, t = threadIdx.x;
    int own = cnt[(b << 10) + t];
    a[t] = own;
    __syncthreads();
    for (int s = 1; s < 1024; s <<= 1) {
        int v = (t >= s) ? a[t - s] : 0;
        __syncthreads();
        a[t] += v;
        __syncthreads();
    }
    offs[(b << 10) + t] = a[t] - own;
}
__global__ void k_fill(const int* __restrict__ edges, const int* __restrict__ offs,
                       int* __restrict__ cur, int* __restrict__ elist) {
    int i = blockIdx.x * 256 + threadIdx.x;
    int2 e = *(const int2*)&edges[(size_t)i * 2];
    int b = i >> 13, t = i & (NT - 1);
    int ps = atomicAdd(&cur[(b << 10) + e.x], 1);
    elist[(b << 14) + offs[(b << 10) + e.x] + ps] = t * 2;
    int po = atomicAdd(&cur[(b << 10) + e.y], 1);
    elist[(b << 14) + offs[(b << 10) + e.y] + po] = t * 2 + 1;
}
__global__ void k_pool(const unsigned short* __restrict__ sob, const int* __restrict__ cnt,
                       const int* __restrict__ offs, const int* __restrict__ elist,
                       float* __restrict__ pooled) {
    int w = (blockIdx.x * 256 + threadIdx.x) >> 6;
    int lane = threadIdx.x & 63;
    if (lane >= 48) return;
    int b = w >> 10, o = w & (NO - 1);
    int len = cnt[(b << 10) + o];
    const int* lst = elist + (b << 14) + offs[(b << 10) + o];
    f32x4 a0 = {0.f, 0.f, 0.f, 0.f}, a1 = {0.f, 0.f, 0.f, 0.f};
    f32x4 c0 = {0.f, 0.f, 0.f, 0.f}, c1 = {0.f, 0.f, 0.f, 0.f};
    int j = 0;
    for (; j + 1 < len; j += 2) {
        int e0 = lst[j], e1 = lst[j + 1];
        bf16x8 v0 = *(const bf16x8*)(sob + ((size_t)((b << 13) + (e0 >> 1))) * 768 + (e0 & 1) * DD + lane * 8);
        bf16x8 v1 = *(const bf16x8*)(sob + ((size_t)((b << 13) + (e1 >> 1))) * 768 + (e1 & 1) * DD + lane * 8);
        a0[0] += bf2f((unsigned short)v0[0]); a0[1] += bf2f((unsigned short)v0[1]);
        a0[2] += bf2f((unsigned short)v0[2]); a0[3] += bf2f((unsigned short)v0[3]);
        a1[0] += bf2f((unsigned short)v0[4]); a1[1] += bf2f((unsigned short)v0[5]);
        a1[2] += bf2f((unsigned short)v0[6]); a1[3] += bf2f((unsigned short)v0[7]);
        c0[0] += bf2f((unsigned short)v1[0]); c0[1] += bf2f((unsigned short)v1[1]);
        c0[2] += bf2f((unsigned short)v1[2]); c0[3] += bf2f((unsigned short)v1[3]);
        c1[0] += bf2f((unsigned short)v1[4]); c1[1] += bf2f((unsigned short)v1[5]);
        c1[2] += bf2f((unsigned short)v1[6]); c1[3] += bf2f((unsigned short)v1[7]);
    }
    if (j < len) {
        int e0 = lst[j];
        bf16x8 v0 = *(const bf16x8*)(sob + ((size_t)((b << 13) + (e0 >> 1))) * 768 + (e0 & 1) * DD + lane * 8);
        a0[0] += bf2f((unsigned short)v0[0]); a0[1] += bf2f((unsigned short)v0[1]);
        a0[2] += bf2f((unsigned short)v0[2]); a0[3] += bf2f((unsigned short)v0[3]);
        a1[0] += bf2f((unsigned short)v0[4]); a1[1] += bf2f((unsigned short)v0[5]);
        a1[2] += bf2f((unsigned short)v0[6]); a1[3] += bf2f((unsigned short)v0[7]);
    }
    a0 += c0; a1 += c1;
    float* dst = pooled + ((size_t)((b << 10) + o)) * DD + lane * 8;
    *(f32x4*)dst = a0;
    *(f32x4*)(dst + 4) = a1;
}

// ---------- 128x192-tile pipelined gather-GEMM1 (80KB LDS, 2 blocks/CU) + setprio ----------
__launch_bounds__(256, 2)
__global__ void gemm_g1(const unsigned short* __restrict__ objb,
                        const float* __restrict__ predf,
                        const int* __restrict__ edges,
                        const unsigned short* __restrict__ Bt,
                        const float* __restrict__ bias,
                        unsigned short* __restrict__ outb)
{
    const int tid = threadIdx.x;
    const int lane = tid & 63;
    const int d = blockIdx.x;
    const int chunk = gridDim.x >> 3;
    const int bid = (d & 7) * chunk + (d >> 3);
    const int xb = bid >> 1, nb = bid & 1;
    const int m0 = xb * 128;
    const int btrow = nb * 192;

    __shared__ unsigned short lds[2][20480];   // [buf][A:0..8191 | B:8192..20479]

    const int rb = tid >> 3;                   // 0..31
    const int c8 = ((tid & 7) ^ (rb & 7)) * 8;

    const int bb = (m0 >> 13) << 10;
    int er0[4], er1[4];
#pragma unroll
    for (int i = 0; i < 4; ++i) {
        int2 e = *(const int2*)&edges[(size_t)(m0 + i * 32 + rb) * 2];
        er0[i] = bb + e.x;
        er1[i] = bb + e.y;
    }

    f32x4 acc[4][6];
#pragma unroll
    for (int i = 0; i < 4; ++i)
#pragma unroll
        for (int j = 0; j < 6; ++j) acc[i][j] = (f32x4){0.f, 0.f, 0.f, 0.f};

    const int wid = tid >> 6, wm = wid >> 1, wn = wid & 1;
    const int l16 = lane & 15, lg = lane >> 4;

    // prologue: tile 0 (seg 0 = subj)
#pragma unroll
    for (int i = 0; i < 4; ++i)
        gload16(objb + (size_t)er0[i] * DD + c8, &lds[0][i * 2048 + tid * 8]);
#pragma unroll
    for (int i = 0; i < 6; ++i)
        gload16(Bt + (size_t)(btrow + i * 32 + rb) * K1 + c8, &lds[0][8192 + i * 2048 + tid * 8]);

    const int nsteps = K1 / 64;    // 18
    for (int t = 0; t < nsteps; ++t) {
        const int cur = t & 1;
        const int tn = t + 1;
        if (tn < nsteps) {
            const int nseg = tn / 6;
            const int ko = (tn - nseg * 6) * 64;   // local offset within segment
            if (nseg == 1) {
                // pred: f32 reg loads (implicit precise wait before pack8 retires
                // them AND all older staging loads); B gloads stay in flight.
                f32x4 pf[4][2];
#pragma unroll
                for (int i = 0; i < 4; ++i) {
                    const float* p = predf + (size_t)(m0 + i * 32 + rb) * DD + ko + c8;
                    pf[i][0] = *(const f32x4*)p;
                    pf[i][1] = *(const f32x4*)(p + 4);
                }
#pragma unroll
                for (int i = 0; i < 6; ++i)
                    gload16(Bt + (size_t)(btrow + i * 32 + rb) * K1 + tn * 64 + c8,
                            &lds[cur ^ 1][8192 + i * 2048 + tid * 8]);
#pragma unroll
                for (int i = 0; i < 4; ++i)
                    *(bf16x8*)(&lds[cur ^ 1][i * 2048 + tid * 8]) = pack8(pf[i][0], pf[i][1]);
            } else {
#pragma unroll
                for (int i = 0; i < 4; ++i) {
                    int row = (nseg == 0) ? er0[i] : er1[i];
                    gload16(objb + (size_t)row * DD + ko + c8, &lds[cur ^ 1][i * 2048 + tid * 8]);
                }
#pragma unroll
                for (int i = 0; i < 6; ++i)
                    gload16(Bt + (size_t)(btrow + i * 32 + rb) * K1 + tn * 64 + c8,
                            &lds[cur ^ 1][8192 + i * 2048 + tid * 8]);
                asm volatile("s_waitcnt vmcnt(10)" ::: "memory");
            }
        } else {
            asm volatile("s_waitcnt vmcnt(0)" ::: "memory");
        }
        __builtin_amdgcn_s_barrier();
        const unsigned short* At = &lds[cur][0];
        const unsigned short* Bl = &lds[cur][8192];
        __builtin_amdgcn_s_setprio(1);
#pragma unroll
        for (int kt = 0; kt < 2; ++kt) {
            const int cs = ((kt * 4 + lg) ^ (l16 & 7)) * 8;
            bf16x8 af[4], bfr[6];
#pragma unroll
            for (int mt = 0; mt < 4; ++mt)
                af[mt] = *(const bf16x8*)(At + (wm * 64 + mt * 16 + l16) * 64 + cs);
#pragma unroll
            for (int nn = 0; nn < 6; ++nn)
                bfr[nn] = *(const bf16x8*)(Bl + (wn * 96 + nn * 16 + l16) * 64 + cs);
#pragma unroll
            for (int mt = 0; mt < 4; ++mt)
#pragma unroll
                for (int nn = 0; nn < 6; ++nn)
                    acc[mt][nn] = __builtin_amdgcn_mfma_f32_16x16x32_bf16(af[mt], bfr[nn], acc[mt][nn], 0, 0, 0);
        }
        __builtin_amdgcn_s_setprio(0);
        asm volatile("s_waitcnt lgkmcnt(0)" ::: "memory");
        __builtin_amdgcn_s_barrier();
    }

#pragma unroll
    for (int nn = 0; nn < 6; ++nn) {
        int gn = btrow + wn * 96 + nn * 16 + l16;
        float bv = bias[gn];
#pragma unroll
        for (int mt = 0; mt < 4; ++mt) {
            int rbase = wm * 64 + mt * 16 + lg * 4;
#pragma unroll
            for (int rg = 0; rg < 4; ++rg) {
                int gr = m0 + rbase + rg;
                float v = fmaxf(acc[mt][nn][rg] + bv, 0.0f);
                outb[(size_t)gr * DD + gn] = f2bf(v);
            }
        }
    }
}

// ---------- 128x192-tile pipelined GEMM (80KB LDS, 2 blocks/CU) + setprio ----------
template <int EPI>
__launch_bounds__(256, 2)
__global__ void gemm_p(const unsigned short* __restrict__ Abf,
                       const unsigned short* __restrict__ Bt,
                       const float* __restrict__ bias,
                       unsigned short* __restrict__ outb,
                       float* __restrict__ outf,
                       int K, int ldC, int nbn, int osplit, int oadd)
{
    const int tid = threadIdx.x;
    const int lane = tid & 63;
    const int d = blockIdx.x;
    const int chunk = gridDim.x >> 3;
    const int bid = (d & 7) * chunk + (d >> 3);
    const int xb = bid / nbn, nb = bid - xb * nbn;
    const int m0 = xb * 128;
    const int btrow = nb * 192 + (nb >= osplit ? oadd : 0);
    const int col0 = nb * 192;

    __shared__ unsigned short lds[2][20480];

    const int rb = tid >> 3;
    const int c8 = ((tid & 7) ^ (rb & 7)) * 8;

    f32x4 acc[4][6];
#pragma unroll
    for (int i = 0; i < 4; ++i)
#pragma unroll
        for (int j = 0; j < 6; ++j) acc[i][j] = (f32x4){0.f, 0.f, 0.f, 0.f};

    const int wid = tid >> 6, wm = wid >> 1, wn = wid & 1;
    const int l16 = lane & 15, lg = lane >> 4;

#define STAGE_P(BUF, KK)                                                                   \
    {                                                                                      \
        _Pragma("unroll")                                                                  \
        for (int i = 0; i < 6; ++i)                                                        \
            gload16(Bt + (size_t)(btrow + i * 32 + rb) * K + (KK) + c8,                    \
                    &lds[BUF][8192 + i * 2048 + tid * 8]);                                 \
        _Pragma("unroll")                                                                  \
        for (int i = 0; i < 4; ++i)                                                        \
            gload16(Abf + (size_t)(m0 + i * 32 + rb) * K + (KK) + c8,                      \
                    &lds[BUF][i * 2048 + tid * 8]);                                        \
    }

    const int nt = K / 64;
    STAGE_P(0, 0)
    for (int t = 0; t < nt; ++t) {
        const int cur = t & 1;
        if (t + 1 < nt) {
            STAGE_P(cur ^ 1, (t + 1) * 64)
            asm volatile("s_waitcnt vmcnt(10)" ::: "memory");
        } else {
            asm volatile("s_waitcnt vmcnt(0)" ::: "memory");
        }
        __builtin_amdgcn_s_barrier();
        const unsigned short* At = &lds[cur][0];
        const unsigned short* Bl = &lds[cur][8192];
        __builtin_amdgcn_s_setprio(1);
#pragma unroll
        for (int kt = 0; kt < 2; ++kt) {
            const int cs = ((kt * 4 + lg) ^ (l16 & 7)) * 8;
            bf16x8 af[4], bfr[6];
#pragma unroll
            for (int mt = 0; mt < 4; ++mt)
                af[mt] = *(const bf16x8*)(At + (wm * 64 + mt * 16 + l16) * 64 + cs);
#pragma unroll
            for (int nn = 0; nn < 6; ++nn)
                bfr[nn] = *(const bf16x8*)(Bl + (wn * 96 + nn * 16 + l16) * 64 + cs);
#pragma unroll
            for (int mt = 0; mt < 4; ++mt)
#pragma unroll
                for (int nn = 0; nn < 6; ++nn)
                    acc[mt][nn] = __builtin_amdgcn_mfma_f32_16x16x32_bf16(af[mt], bfr[nn], acc[mt][nn], 0, 0, 0);
        }
        __builtin_amdgcn_s_setprio(0);
        asm volatile("s_waitcnt lgkmcnt(0)" ::: "memory");
        __builtin_amdgcn_s_barrier();
    }
#undef STAGE_P

#pragma unroll
    for (int nn = 0; nn < 6; ++nn) {
        int gnl = wn * 96 + nn * 16 + l16;
        float bv = bias[btrow + gnl];
#pragma unroll
        for (int mt = 0; mt < 4; ++mt) {
            int rbase = wm * 64 + mt * 16 + lg * 4;
#pragma unroll
            for (int rg = 0; rg < 4; ++rg) {
                int gr = m0 + rbase + rg;
                float v = fmaxf(acc[mt][nn][rg] + bv, 0.0f);
                if (EPI == 0) outb[(size_t)gr * ldC + col0 + gnl] = f2bf(v);
                else          outf[(size_t)gr * ldC + col0 + gnl] = v;
            }
        }
    }
}

extern "C" void kernel_launch(void* const* d_in, const int* in_sizes, int n_in,
                              void* d_out, int out_size, void* d_ws, size_t ws_size,
                              hipStream_t stream)
{
    const float* obj  = (const float*)d_in[0];
    const float* pred = (const float*)d_in[1];
    const int* edges  = (const int*)d_in[2];
    const float* w1a  = (const float*)d_in[3];
    const float* b1a  = (const float*)d_in[4];
    const float* w1b  = (const float*)d_in[5];
    const float* b1b  = (const float*)d_in[6];
    const float* w2a  = (const float*)d_in[7];
    const float* b2a  = (const float*)d_in[8];
    const float* w2b  = (const float*)d_in[9];
    const float* b2b  = (const float*)d_in[10];

    float* out_obj = (float*)d_out;                  // [8192][384] f32
    float* newp    = out_obj + (size_t)MO * DD;      // [65536][384] f32
    unsigned short* sob = (unsigned short*)newp;     // temp alias: [65536][768] bf16

    unsigned short* objb = (unsigned short*)d_ws;
    unsigned short* w1aT = objb + (size_t)NB * NO * DD;
    unsigned short* w1bT = w1aT + (size_t)DD * K1;
    unsigned short* w2aT = w1bT + (size_t)K1 * DD;
    unsigned short* w2bT = w2aT + (size_t)DD * DD;
    unsigned short* hbuf = w2bT + (size_t)DD * DD;                 // [65536][384] bf16
    float* pooled = (float*)(hbuf + (size_t)M1 * DD);              // [8192][384] f32
    float* sumsq  = pooled + (size_t)MO * DD;                      // 1 f32 (+pad)
    unsigned short* hid2 = (unsigned short*)(sumsq + 4);           // [8192][384] bf16
    int* cnt   = (int*)(hid2 + (size_t)MO * DD);                   // 8192
    int* cur   = cnt + NB * NO;
    int* offs  = cur + NB * NO;
    int* elist = offs + NB * NO;                                   // 131072
    float* partial = (float*)(elist + 2 * M1);                     // 128
    unsigned short* poolb = objb;                                  // alias: objb dead after GEMM1

    // prep
    hipLaunchKernelGGL(k_cvt4, dim3(3072), dim3(256), 0, stream, obj, objb, NB * NO * DD);
    hipLaunchKernelGGL(k_tr, dim3(K1, 3), dim3(128), 0, stream, w1a, w1aT, K1, DD);
    hipLaunchKernelGGL(k_tr, dim3(DD, 9), dim3(128), 0, stream, w1b, w1bT, DD, K1);
    hipLaunchKernelGGL(k_tr, dim3(DD, 3), dim3(128), 0, stream, w2a, w2aT, DD, DD);
    hipLaunchKernelGGL(k_tr, dim3(DD, 3), dim3(128), 0, stream, w2b, w2bT, DD, DD);
    hipMemsetAsync(cnt, 0, 2 * NB * NO * sizeof(int), stream);

    // GEMM1: hbuf = relu(gather(triple) @ w1a + b1a) — 512m x 2n = 1024 blocks
    hipLaunchKernelGGL(gemm_g1, dim3(2 * M1 / 128), dim3(256), 0, stream,
                       objb, pred, edges, w1aT, b1a, hbuf);

    // GEMM2 s+o -> sob: 512m x 4n = 2048 blocks; nb<2 -> w1b rows nb*192 (s),
    // nb>=2 -> rows nb*192+384 (o); out cols nb*192 of ld=768.
    hipLaunchKernelGGL((gemm_p<0>), dim3(4 * M1 / 128), dim3(256), 0, stream,
                       hbuf, w1bT, b1b, sob, (float*)nullptr, DD, 2 * DD, 4, 2, DD);

    // CSR build + pooled gather-reduce
    hipLaunchKernelGGL(k_hist, dim3(256), dim3(256), 0, stream, edges, cnt);
    hipLaunchKernelGGL(k_scan, dim3(8), dim3(1024), 0, stream, cnt, offs);
    hipLaunchKernelGGL(k_fill, dim3(256), dim3(256), 0, stream, edges, offs, cur, elist);
    hipLaunchKernelGGL(k_pool, dim3(2048), dim3(256), 0, stream, sob, cnt, offs, elist, pooled);

    // newp = relu(h @ w1b[:,384:768] + b1b[384:768]) — rows 384+nb*192 (osplit=0, oadd=384)
    hipLaunchKernelGGL((gemm_p<2>), dim3(2 * M1 / 128), dim3(256), 0, stream,
                       hbuf, w1bT, b1b, (unsigned short*)nullptr, newp, DD, DD, 2, 0, DD);

    // ||pooled||^2 two-stage, then normalize+cvt
    hipLaunchKernelGGL(k_ss1, dim3(128), dim3(256), 0, stream, pooled, partial, MO * DD / 4);
    hipLaunchKernelGGL(k_ss2, dim3(1), dim3(128), 0, stream, partial, sumsq);
    hipLaunchKernelGGL(k_normcvt, dim3(1536), dim3(256), 0, stream, pooled, sumsq, poolb);

    // D1: hid2 = relu(poolb @ w2a + b2a) — 64m x 2n = 128 blocks
    hipLaunchKernelGGL((gemm_p<0>), dim3(2 * MO / 128), dim3(256), 0, stream,
                       poolb, w2aT, b2a, hid2, (float*)nullptr, DD, DD, 2, 2, 0);

    // D2: out_obj = relu(hid2 @ w2b + b2b)
    hipLaunchKernelGGL((gemm_p<2>), dim3(2 * MO / 128), dim3(256), 0, stream,
                       hid2, w2bT, b2b, (unsigned short*)nullptr, out_obj, DD, DD, 2, 2, 0);
}